// Round 1
// baseline (367.923 us; speedup 1.0000x reference)
//
#include <hip/hip_runtime.h>

#define N_NODES 20000
#define N_EDGES 320000
#define DD      256
#define D2      512
#define M_PAD   20032   // 20000 padded to multiple of 64

typedef short short8 __attribute__((ext_vector_type(8)));
typedef float f32x4  __attribute__((ext_vector_type(4)));

__device__ __forceinline__ unsigned short f2b(float f) {
    unsigned u = __float_as_uint(f);
    u = u + 0x7fffu + ((u >> 16) & 1u);   // round-to-nearest-even
    return (unsigned short)(u >> 16);
}
__device__ __forceinline__ float b2f(unsigned short b) {
    return __uint_as_float(((unsigned)b) << 16);
}

// ---------------- K1: degree count + W transpose->bf16 + x cast->bf16 ----------------
__global__ void k1_prep(const int* __restrict__ edge, const float* __restrict__ x,
                        const float* __restrict__ Wg, int* __restrict__ cnt,
                        unsigned short* __restrict__ WT, unsigned short* __restrict__ xb) {
    int blk = blockIdx.x, tid = threadIdx.x;
    if (blk < 1250) {                       // count in-degrees over real edges
        int e = blk * 256 + tid;
        if (e < N_EDGES) atomicAdd(&cnt[edge[2 * e + 1]], 1);
    } else if (blk < 1506) {                // W_gcn (256x512) -> WT bf16 (512x256)
        int i = (blk - 1250) * 256 + tid;
        #pragma unroll
        for (int r = 0; r < 2; r++) {
            int idx = i + r * 65536;        // 131072 elements
            int k = idx >> 9, n = idx & 511;
            WT[n * 256 + k] = f2b(Wg[idx]);
        }
    } else {                                // x -> bf16 copy
        int i = (blk - 1506) * 256 + tid;   // exactly 5,120,000
        xb[i] = f2b(x[i]);
    }
}

// ---------------- K2: single-block scan -> offsets, cursor, dinv ----------------
__global__ void k2_scan(const int* __restrict__ cnt, int* __restrict__ offs,
                        int* __restrict__ cursor, float* __restrict__ dinv) {
    __shared__ int wsum[16];
    int t = threadIdx.x;
    const int C = 20;                       // 1024*20 = 20480 >= 20000
    int b0 = t * C;
    int vals[20];
    int s = 0;
    #pragma unroll
    for (int j = 0; j < C; j++) {
        int i = b0 + j;
        int v = (i < N_NODES) ? cnt[i] : 0;
        vals[j] = v;
        s += v;
    }
    int lane = t & 63, wid = t >> 6;
    int incl = s;
    #pragma unroll
    for (int off = 1; off < 64; off <<= 1) {
        int u = __shfl_up(incl, off, 64);
        if (lane >= off) incl += u;
    }
    if (lane == 63) wsum[wid] = incl;
    __syncthreads();
    if (wid == 0) {
        int v2 = (lane < 16) ? wsum[lane] : 0;
        #pragma unroll
        for (int off = 1; off < 16; off <<= 1) {
            int u = __shfl_up(v2, off, 64);
            if (lane >= off) v2 += u;
        }
        if (lane < 16) wsum[lane] = v2;     // inclusive scan of wave sums
    }
    __syncthreads();
    int wbase = (wid == 0) ? 0 : wsum[wid - 1];
    int run = wbase + incl - s;             // exclusive prefix of this thread's chunk
    #pragma unroll
    for (int j = 0; j < C; j++) {
        int i = b0 + j;
        if (i < N_NODES) {
            offs[i] = run;
            cursor[i] = run;
            dinv[i] = rsqrtf((float)(vals[j] + 1));   // deg = cnt + self-loop
            run += vals[j];
        }
    }
    if (t == 1023) offs[N_NODES] = run;     // = 320000
}

// ---------------- K3: CSR fill ----------------
__global__ void k3_fill(const int* __restrict__ edge, int* __restrict__ cursor,
                        int* __restrict__ csr) {
    int e = blockIdx.x * 256 + threadIdx.x;
    if (e < N_EDGES) {
        int s = edge[2 * e], d = edge[2 * e + 1];
        int pos = atomicAdd(&cursor[d], 1);
        csr[pos] = s;
    }
}

// ---------------- K4: per-node aggregation of x rows -> aggX (bf16) ----------------
__global__ void k4_agg(const int* __restrict__ offs, const int* __restrict__ csr,
                       const float* __restrict__ dinv, const unsigned short* __restrict__ xb,
                       unsigned short* __restrict__ aggX) {
    int n = blockIdx.x, t = threadIdx.x;
    if (n >= N_NODES) { aggX[(size_t)n * DD + t] = 0; return; }   // zero pad rows
    int beg = offs[n], end = offs[n + 1];
    float acc = 0.f;
    for (int e = beg; e < end; e++) {
        int s = csr[e];
        acc += dinv[s] * b2f(xb[(size_t)s * DD + t]);
    }
    float dn = dinv[n];
    acc = dn * acc + dn * dn * b2f(xb[(size_t)n * DD + t]);       // self-loop
    aggX[(size_t)n * DD + t] = f2b(acc);
}

// ---------------- K5: bf16 MFMA GEMM (20032x256 @ 256x512) with fused relu+bias+row-sum ----------------
__global__ void __launch_bounds__(256, 2)
k5_gemm(const unsigned short* __restrict__ aggX, const unsigned short* __restrict__ WT,
        const float* __restrict__ bg, float* __restrict__ h) {
    __shared__ float hblk[D2];
    int tid = threadIdx.x;
    hblk[tid] = 0.f; hblk[tid + 256] = 0.f;
    int w = tid >> 6, lane = tid & 63;
    int quad = lane >> 4, l15 = lane & 15;
    int row = blockIdx.x * 64 + w * 16 + l15;
    f32x4 acc[32];
    #pragma unroll
    for (int nt = 0; nt < 32; nt++) acc[nt] = (f32x4){0.f, 0.f, 0.f, 0.f};
    #pragma unroll 1
    for (int kt = 0; kt < 8; kt++) {
        short8 a = *(const short8*)(aggX + (size_t)row * DD + kt * 32 + quad * 8);
        #pragma unroll
        for (int nt = 0; nt < 32; nt++) {
            short8 b = *(const short8*)(WT + (size_t)(nt * 16 + l15) * DD + kt * 32 + quad * 8);
            acc[nt] = __builtin_amdgcn_mfma_f32_16x16x32_bf16(a, b, acc[nt], 0, 0, 0);
        }
    }
    __syncthreads();
    int rowbase = blockIdx.x * 64 + w * 16 + quad * 4;
    #pragma unroll
    for (int nt = 0; nt < 32; nt++) {
        int n = nt * 16 + l15;
        float bias = bg[n];
        float s = 0.f;
        #pragma unroll
        for (int r = 0; r < 4; r++) {
            if (rowbase + r < N_NODES) {
                float v = acc[nt][r] + bias;
                s += v > 0.f ? v : 0.f;
            }
        }
        atomicAdd(&hblk[n], s);
    }
    __syncthreads();
    atomicAdd(&h[tid], hblk[tid]);
    atomicAdd(&h[tid + 256], hblk[tid + 256]);
}

// ---------------- split-K matvec: out[c] += sum_k act(in[k]) * W[k*N+c] ----------------
__global__ void k_mv(const float* __restrict__ in, const float* __restrict__ bias,
                     const float* __restrict__ W, float* __restrict__ out, int N, int act) {
    int c = blockIdx.y * 256 + threadIdx.x;
    int k0 = blockIdx.x * 8;
    float s = 0.f;
    #pragma unroll
    for (int kk = 0; kk < 8; kk++) {
        int k = k0 + kk;
        float v = in[k];
        if (act) { v += bias[k]; v = v > 0.f ? v : 0.f; }
        s += v * W[(size_t)k * N + c];
    }
    atomicAdd(&out[c], s);
}

// ---------------- K9: conv3x3 x2 + softmax(conv) + softmax(front) -> complete[1024] ----------------
__global__ void k9_mid(const float* __restrict__ h, const float* __restrict__ w1, const float* __restrict__ b1,
                       const float* __restrict__ w2, const float* __restrict__ b2,
                       const float* __restrict__ l3raw, const float* __restrict__ bc3,
                       float* __restrict__ complete) {
    __shared__ float img[512];
    __shared__ float c1s[512];
    __shared__ float red[512];
    int t = threadIdx.x;
    img[t] = h[t];
    __syncthreads();
    int y = t >> 4, x = t & 15;
    float s = 0.f;
    #pragma unroll
    for (int dy = -1; dy <= 1; dy++)
        #pragma unroll
        for (int dx = -1; dx <= 1; dx++) {
            int yy = y + dy, xc = x + dx;
            if (yy >= 0 && yy < 32 && xc >= 0 && xc < 16)
                s += w1[(dy + 1) * 3 + (dx + 1)] * img[yy * 16 + xc];
        }
    s += b1[0];
    c1s[t] = s > 0.f ? s : 0.f;
    __syncthreads();
    float s2 = 0.f;
    #pragma unroll
    for (int dy = -1; dy <= 1; dy++)
        #pragma unroll
        for (int dx = -1; dx <= 1; dx++) {
            int yy = y + dy, xc = x + dx;
            if (yy >= 0 && yy < 32 && xc >= 0 && xc < 16)
                s2 += w2[(dy + 1) * 3 + (dx + 1)] * c1s[yy * 16 + xc];
        }
    s2 += b2[0];
    float v2 = s2 > 0.f ? s2 : 0.f;
    // softmax over conv output
    red[t] = v2; __syncthreads();
    for (int off = 256; off > 0; off >>= 1) { if (t < off) red[t] = fmaxf(red[t], red[t + off]); __syncthreads(); }
    float m = red[0]; __syncthreads();
    float e = expf(v2 - m);
    red[t] = e; __syncthreads();
    for (int off = 256; off > 0; off >>= 1) { if (t < off) red[t] += red[t + off]; __syncthreads(); }
    complete[t] = e / red[0];
    __syncthreads();
    // front softmax
    float z = l3raw[t] + bc3[t];
    red[t] = z; __syncthreads();
    for (int off = 256; off > 0; off >>= 1) { if (t < off) red[t] = fmaxf(red[t], red[t + off]); __syncthreads(); }
    float m2 = red[0]; __syncthreads();
    float e2 = expf(z - m2);
    red[t] = e2; __syncthreads();
    for (int off = 256; off > 0; off >>= 1) { if (t < off) red[t] += red[t + off]; __syncthreads(); }
    complete[512 + t] = e2 / red[0];
}

// ---------------- K12: p2 relu -> p3 -> sigmoid output ----------------
__global__ void k12_final(const float* __restrict__ p2raw, const float* __restrict__ bp2,
                          const float* __restrict__ Wp3, const float* __restrict__ bp3,
                          const float* __restrict__ Wp4, const float* __restrict__ bp4,
                          float* __restrict__ out) {
    __shared__ float p2s[256];
    __shared__ float p3s[128];
    int t = threadIdx.x;
    float v = p2raw[t] + bp2[t];
    p2s[t] = v > 0.f ? v : 0.f;
    __syncthreads();
    if (t < 128) {
        float s = bp3[t];
        #pragma unroll 8
        for (int k = 0; k < 256; k++) s += p2s[k] * Wp3[k * 128 + t];
        p3s[t] = s > 0.f ? s : 0.f;
    }
    __syncthreads();
    if (t < 2) {
        float s = bp4[t];
        for (int k = 0; k < 128; k++) s += p3s[k] * Wp4[k * 2 + t];
        out[t] = 1.f / (1.f + expf(-s));
    }
}

extern "C" void kernel_launch(void* const* d_in, const int* in_sizes, int n_in,
                              void* d_out, int out_size, void* d_ws, size_t ws_size,
                              hipStream_t stream) {
    const float* x    = (const float*)d_in[0];
    const int*   edge = (const int*)d_in[1];
    const float* Wg   = (const float*)d_in[2];
    const float* bg   = (const float*)d_in[3];
    const float* c1w  = (const float*)d_in[4];
    const float* c1b  = (const float*)d_in[5];
    const float* c2w  = (const float*)d_in[6];
    const float* c2b  = (const float*)d_in[7];
    const float* Wc1  = (const float*)d_in[8];
    const float* bc1  = (const float*)d_in[9];
    const float* Wc2  = (const float*)d_in[10];
    const float* bc2  = (const float*)d_in[11];
    const float* Wc3  = (const float*)d_in[12];
    const float* bc3  = (const float*)d_in[13];
    const float* Wp1  = (const float*)d_in[14];
    const float* bp1  = (const float*)d_in[15];
    const float* Wp2  = (const float*)d_in[16];
    const float* bp2  = (const float*)d_in[17];
    const float* Wp3  = (const float*)d_in[18];
    const float* bp3  = (const float*)d_in[19];
    const float* Wp4  = (const float*)d_in[20];
    const float* bp4  = (const float*)d_in[21];
    float* out = (float*)d_out;

    char* ws = (char*)d_ws;
    // workspace layout (bytes); zero-region = [0, 91264)
    int*   cnt     = (int*)(ws + 0);            // 20000 ints
    float* h       = (float*)(ws + 80000);      // 512
    float* f1raw   = (float*)(ws + 82048);      // 512
    float* f2raw   = (float*)(ws + 84096);      // 512
    float* l3raw   = (float*)(ws + 86144);      // 512
    float* p1raw   = (float*)(ws + 88192);      // 512
    float* p2raw   = (float*)(ws + 90240);      // 256 (ends 91264)
    int*   offs    = (int*)(ws + 91264);        // 20001 ints
    int*   cursor  = (int*)(ws + 171280);       // 20000 ints
    float* dinv    = (float*)(ws + 251280);     // 20000
    int*   csr     = (int*)(ws + 331280);       // 320000 ints
    unsigned short* WT   = (unsigned short*)(ws + 1611280);   // 512x256 bf16
    unsigned short* aggX = (unsigned short*)(ws + 1873424);   // 20032x256 bf16
    unsigned short* xb   = (unsigned short*)(ws + 12129808);  // 20000x256 bf16
    float* complete = (float*)(ws + 22369808);  // 1024
    (void)ws_size; (void)in_sizes; (void)n_in; (void)out_size;

    hipMemsetAsync(d_ws, 0, 91264, stream);

    k1_prep<<<21506, 256, 0, stream>>>(edge, x, Wg, cnt, WT, xb);
    k2_scan<<<1, 1024, 0, stream>>>(cnt, offs, cursor, dinv);
    k3_fill<<<1250, 256, 0, stream>>>(edge, cursor, csr);
    k4_agg<<<M_PAD, 256, 0, stream>>>(offs, csr, dinv, xb, aggX);
    k5_gemm<<<313, 256, 0, stream>>>(aggX, WT, bg, h);
    k_mv<<<dim3(64, 2), 256, 0, stream>>>(h,     nullptr, Wc1, f1raw, 512, 0);
    k_mv<<<dim3(64, 2), 256, 0, stream>>>(f1raw, bc1,     Wc2, f2raw, 512, 1);
    k_mv<<<dim3(64, 2), 256, 0, stream>>>(f2raw, bc2,     Wc3, l3raw, 512, 1);
    k9_mid<<<1, 512, 0, stream>>>(h, c1w, c1b, c2w, c2b, l3raw, bc3, complete);
    k_mv<<<dim3(128, 2), 256, 0, stream>>>(complete, nullptr, Wp1, p1raw, 512, 0);
    k_mv<<<dim3(64, 1), 256, 0, stream>>>(p1raw, bp1, Wp2, p2raw, 256, 1);
    k12_final<<<1, 256, 0, stream>>>(p2raw, bp2, Wp3, bp3, Wp4, bp4, out);
}

// Round 2
// 283.603 us; speedup vs baseline: 1.2973x; 1.2973x over previous
//
#include <hip/hip_runtime.h>

#define N_NODES 20000
#define N_EDGES 320000
#define DD      256
#define D2      512
#define M_PAD   20032   // 20000 padded to multiple of 64

typedef short short8 __attribute__((ext_vector_type(8)));
typedef float f32x4  __attribute__((ext_vector_type(4)));

__device__ __forceinline__ unsigned f2b(float f) {
    unsigned u = __float_as_uint(f);
    u = u + 0x7fffu + ((u >> 16) & 1u);   // round-to-nearest-even
    return u >> 16;
}
__device__ __forceinline__ float b2f(unsigned short b) {
    return __uint_as_float(((unsigned)b) << 16);
}

// ---------------- K1: degree count + W transpose->bf16 + x cast->bf16 (vectorized) ----------------
__global__ void k1_prep(const int* __restrict__ edge, const float* __restrict__ x,
                        const float* __restrict__ Wg, int* __restrict__ cnt,
                        unsigned short* __restrict__ WT, unsigned short* __restrict__ xb) {
    int blk = blockIdx.x, tid = threadIdx.x;
    if (blk < 1250) {                       // count in-degrees over real edges
        int e = blk * 256 + tid;
        if (e < N_EDGES) atomicAdd(&cnt[edge[2 * e + 1]], 1);
    } else if (blk < 1282) {                // W_gcn (256x512) -> WT bf16 (512x256)
        int i = (blk - 1250) * 256 + tid;
        #pragma unroll
        for (int r = 0; r < 16; r++) {
            int idx = i + r * 8192;         // 131072 elements
            int k = idx >> 9, n = idx & 511;
            WT[n * 256 + k] = (unsigned short)f2b(Wg[idx]);
        }
    } else {                                // x -> bf16, float4 in / uint2 out
        int i = (blk - 1282) * 256 + tid;   // exactly 1,280,000
        float4 v = ((const float4*)x)[i];
        uint2 o;
        o.x = f2b(v.x) | (f2b(v.y) << 16);
        o.y = f2b(v.z) | (f2b(v.w) << 16);
        ((uint2*)xb)[i] = o;
    }
}

// ---------------- K2: single-block scan -> offsets, cursor, dinv ----------------
__global__ void k2_scan(const int* __restrict__ cnt, int* __restrict__ offs,
                        int* __restrict__ cursor, float* __restrict__ dinv) {
    __shared__ int wsum[16];
    int t = threadIdx.x;
    const int C = 20;                       // 1024*20 = 20480 >= 20000
    int b0 = t * C;
    int vals[20];
    int s = 0;
    #pragma unroll
    for (int j = 0; j < C; j++) {
        int i = b0 + j;
        int v = (i < N_NODES) ? cnt[i] : 0;
        vals[j] = v;
        s += v;
    }
    int lane = t & 63, wid = t >> 6;
    int incl = s;
    #pragma unroll
    for (int off = 1; off < 64; off <<= 1) {
        int u = __shfl_up(incl, off, 64);
        if (lane >= off) incl += u;
    }
    if (lane == 63) wsum[wid] = incl;
    __syncthreads();
    if (wid == 0) {
        int v2 = (lane < 16) ? wsum[lane] : 0;
        #pragma unroll
        for (int off = 1; off < 16; off <<= 1) {
            int u = __shfl_up(v2, off, 64);
            if (lane >= off) v2 += u;
        }
        if (lane < 16) wsum[lane] = v2;     // inclusive scan of wave sums
    }
    __syncthreads();
    int wbase = (wid == 0) ? 0 : wsum[wid - 1];
    int run = wbase + incl - s;             // exclusive prefix of this thread's chunk
    #pragma unroll
    for (int j = 0; j < C; j++) {
        int i = b0 + j;
        if (i < N_NODES) {
            offs[i] = run;
            cursor[i] = run;
            dinv[i] = rsqrtf((float)(vals[j] + 1));   // deg = cnt + self-loop
            run += vals[j];
        }
    }
    if (t == 1023) offs[N_NODES] = run;     // = 320000
}

// ---------------- K3: CSR fill ----------------
__global__ void k3_fill(const int* __restrict__ edge, int* __restrict__ cursor,
                        int* __restrict__ csr) {
    int e = blockIdx.x * 256 + threadIdx.x;
    if (e < N_EDGES) {
        int s = edge[2 * e], d = edge[2 * e + 1];
        int pos = atomicAdd(&cursor[d], 1);
        csr[pos] = s;
    }
}

// ---------------- K4: per-node aggregation, wave-per-node, 8B/lane ----------------
__global__ void k4_agg(const int* __restrict__ offs, const int* __restrict__ csr,
                       const float* __restrict__ dinv, const unsigned short* __restrict__ xb,
                       unsigned short* __restrict__ aggX) {
    int wid = threadIdx.x >> 6, lane = threadIdx.x & 63;
    int n = blockIdx.x * 4 + wid;           // < 20032
    float a0 = 0.f, a1 = 0.f, a2 = 0.f, a3 = 0.f;
    if (n < N_NODES) {
        int beg = offs[n], end = offs[n + 1];
        for (int e = beg; e < end; e++) {
            int s = csr[e];
            float dv = dinv[s];
            uint2 u = *(const uint2*)(xb + (size_t)s * DD + lane * 4);
            a0 += dv * __uint_as_float(u.x << 16);
            a1 += dv * __uint_as_float(u.x & 0xffff0000u);
            a2 += dv * __uint_as_float(u.y << 16);
            a3 += dv * __uint_as_float(u.y & 0xffff0000u);
        }
        float dn = dinv[n];
        uint2 u = *(const uint2*)(xb + (size_t)n * DD + lane * 4);
        float dn2 = dn * dn;
        a0 = dn * a0 + dn2 * __uint_as_float(u.x << 16);
        a1 = dn * a1 + dn2 * __uint_as_float(u.x & 0xffff0000u);
        a2 = dn * a2 + dn2 * __uint_as_float(u.y << 16);
        a3 = dn * a3 + dn2 * __uint_as_float(u.y & 0xffff0000u);
    }
    uint2 o;
    o.x = f2b(a0) | (f2b(a1) << 16);
    o.y = f2b(a2) | (f2b(a3) << 16);
    *(uint2*)(aggX + (size_t)n * DD + lane * 4) = o;
}

// ---------------- K5: bf16 MFMA GEMM (20032x256 @ 256x512), B tile in LDS, fused relu+bias+row-sum ----------------
#define TN 128   // cols per block
__global__ void __launch_bounds__(256, 2)
k5_gemm(const unsigned short* __restrict__ aggX, const unsigned short* __restrict__ WT,
        const float* __restrict__ bg, float* __restrict__ h) {
    __shared__ unsigned short bsh[TN * 264];   // 264 = 256 + 8 pad -> conflict-free ds_read_b128
    __shared__ float hblk[TN];
    int tid = threadIdx.x;
    int rowblk = blockIdx.x;      // 0..312
    int ct = blockIdx.y;          // 0..3
    // stage B tile: WT rows [ct*128, ct*128+128), 256 k each. 4096 16B-chunks, 16/thread.
    #pragma unroll
    for (int i = 0; i < 16; i++) {
        int c = tid + i * 256;
        int r = c >> 5;                    // 32 chunks per row
        int kc = (c & 31) << 3;
        *(short8*)(&bsh[r * 264 + kc]) = *(const short8*)(WT + (size_t)(ct * TN + r) * DD + kc);
    }
    if (tid < TN) hblk[tid] = 0.f;
    __syncthreads();

    int w = tid >> 6, lane = tid & 63;
    int quad = lane >> 4, l15 = lane & 15;
    int row = rowblk * 64 + w * 16 + l15;
    f32x4 acc[8];
    #pragma unroll
    for (int nt = 0; nt < 8; nt++) acc[nt] = (f32x4){0.f, 0.f, 0.f, 0.f};
    #pragma unroll
    for (int kt = 0; kt < 8; kt++) {
        short8 a = *(const short8*)(aggX + (size_t)row * DD + kt * 32 + quad * 8);
        #pragma unroll
        for (int nt = 0; nt < 8; nt++) {
            short8 b = *(const short8*)(&bsh[(nt * 16 + l15) * 264 + kt * 32 + quad * 8]);
            acc[nt] = __builtin_amdgcn_mfma_f32_16x16x32_bf16(a, b, acc[nt], 0, 0, 0);
        }
    }
    int rowbase = rowblk * 64 + w * 16 + quad * 4;
    #pragma unroll
    for (int nt = 0; nt < 8; nt++) {
        int cl = nt * 16 + l15;
        float bias = bg[ct * TN + cl];
        float s = 0.f;
        #pragma unroll
        for (int r = 0; r < 4; r++) {
            if (rowbase + r < N_NODES) {
                float v = acc[nt][r] + bias;
                s += v > 0.f ? v : 0.f;
            }
        }
        atomicAdd(&hblk[cl], s);
    }
    __syncthreads();
    if (tid < TN) atomicAdd(&h[ct * TN + tid], hblk[tid]);
}

// ---------------- split-K matvec: out[c] += sum_k act(in[k]) * W[k*N+c] ----------------
__global__ void k_mv(const float* __restrict__ in, const float* __restrict__ bias,
                     const float* __restrict__ W, float* __restrict__ out, int N, int act) {
    int c = blockIdx.y * 256 + threadIdx.x;
    int k0 = blockIdx.x * 8;
    float s = 0.f;
    #pragma unroll
    for (int kk = 0; kk < 8; kk++) {
        int k = k0 + kk;
        float v = in[k];
        if (act) { v += bias[k]; v = v > 0.f ? v : 0.f; }
        s += v * W[(size_t)k * N + c];
    }
    atomicAdd(&out[c], s);
}

// ---------------- K9: conv3x3 x2 + softmax(conv) + softmax(front) -> complete[1024] ----------------
__global__ void k9_mid(const float* __restrict__ h, const float* __restrict__ w1, const float* __restrict__ b1,
                       const float* __restrict__ w2, const float* __restrict__ b2,
                       const float* __restrict__ l3raw, const float* __restrict__ bc3,
                       float* __restrict__ complete) {
    __shared__ float img[512];
    __shared__ float c1s[512];
    __shared__ float red[512];
    int t = threadIdx.x;
    img[t] = h[t];
    __syncthreads();
    int y = t >> 4, x = t & 15;
    float s = 0.f;
    #pragma unroll
    for (int dy = -1; dy <= 1; dy++)
        #pragma unroll
        for (int dx = -1; dx <= 1; dx++) {
            int yy = y + dy, xc = x + dx;
            if (yy >= 0 && yy < 32 && xc >= 0 && xc < 16)
                s += w1[(dy + 1) * 3 + (dx + 1)] * img[yy * 16 + xc];
        }
    s += b1[0];
    c1s[t] = s > 0.f ? s : 0.f;
    __syncthreads();
    float s2 = 0.f;
    #pragma unroll
    for (int dy = -1; dy <= 1; dy++)
        #pragma unroll
        for (int dx = -1; dx <= 1; dx++) {
            int yy = y + dy, xc = x + dx;
            if (yy >= 0 && yy < 32 && xc >= 0 && xc < 16)
                s2 += w2[(dy + 1) * 3 + (dx + 1)] * c1s[yy * 16 + xc];
        }
    s2 += b2[0];
    float v2 = s2 > 0.f ? s2 : 0.f;
    red[t] = v2; __syncthreads();
    for (int off = 256; off > 0; off >>= 1) { if (t < off) red[t] = fmaxf(red[t], red[t + off]); __syncthreads(); }
    float m = red[0]; __syncthreads();
    float e = expf(v2 - m);
    red[t] = e; __syncthreads();
    for (int off = 256; off > 0; off >>= 1) { if (t < off) red[t] += red[t + off]; __syncthreads(); }
    complete[t] = e / red[0];
    __syncthreads();
    float z = l3raw[t] + bc3[t];
    red[t] = z; __syncthreads();
    for (int off = 256; off > 0; off >>= 1) { if (t < off) red[t] = fmaxf(red[t], red[t + off]); __syncthreads(); }
    float m2 = red[0]; __syncthreads();
    float e2 = expf(z - m2);
    red[t] = e2; __syncthreads();
    for (int off = 256; off > 0; off >>= 1) { if (t < off) red[t] += red[t + off]; __syncthreads(); }
    complete[512 + t] = e2 / red[0];
}

// ---------------- K12: p2 relu -> p3 -> sigmoid output ----------------
__global__ void k12_final(const float* __restrict__ p2raw, const float* __restrict__ bp2,
                          const float* __restrict__ Wp3, const float* __restrict__ bp3,
                          const float* __restrict__ Wp4, const float* __restrict__ bp4,
                          float* __restrict__ out) {
    __shared__ float p2s[256];
    __shared__ float p3s[128];
    int t = threadIdx.x;
    float v = p2raw[t] + bp2[t];
    p2s[t] = v > 0.f ? v : 0.f;
    __syncthreads();
    if (t < 128) {
        float s = bp3[t];
        #pragma unroll 8
        for (int k = 0; k < 256; k++) s += p2s[k] * Wp3[k * 128 + t];
        p3s[t] = s > 0.f ? s : 0.f;
    }
    __syncthreads();
    if (t < 2) {
        float s = bp4[t];
        for (int k = 0; k < 128; k++) s += p3s[k] * Wp4[k * 2 + t];
        out[t] = 1.f / (1.f + expf(-s));
    }
}

extern "C" void kernel_launch(void* const* d_in, const int* in_sizes, int n_in,
                              void* d_out, int out_size, void* d_ws, size_t ws_size,
                              hipStream_t stream) {
    const float* x    = (const float*)d_in[0];
    const int*   edge = (const int*)d_in[1];
    const float* Wg   = (const float*)d_in[2];
    const float* bg   = (const float*)d_in[3];
    const float* c1w  = (const float*)d_in[4];
    const float* c1b  = (const float*)d_in[5];
    const float* c2w  = (const float*)d_in[6];
    const float* c2b  = (const float*)d_in[7];
    const float* Wc1  = (const float*)d_in[8];
    const float* bc1  = (const float*)d_in[9];
    const float* Wc2  = (const float*)d_in[10];
    const float* bc2  = (const float*)d_in[11];
    const float* Wc3  = (const float*)d_in[12];
    const float* bc3  = (const float*)d_in[13];
    const float* Wp1  = (const float*)d_in[14];
    const float* bp1  = (const float*)d_in[15];
    const float* Wp2  = (const float*)d_in[16];
    const float* bp2  = (const float*)d_in[17];
    const float* Wp3  = (const float*)d_in[18];
    const float* bp3  = (const float*)d_in[19];
    const float* Wp4  = (const float*)d_in[20];
    const float* bp4  = (const float*)d_in[21];
    float* out = (float*)d_out;

    char* ws = (char*)d_ws;
    // workspace layout (bytes); zero-region = [0, 91264)
    int*   cnt     = (int*)(ws + 0);            // 20000 ints
    float* h       = (float*)(ws + 80000);      // 512
    float* f1raw   = (float*)(ws + 82048);      // 512
    float* f2raw   = (float*)(ws + 84096);      // 512
    float* l3raw   = (float*)(ws + 86144);      // 512
    float* p1raw   = (float*)(ws + 88192);      // 512
    float* p2raw   = (float*)(ws + 90240);      // 256 (ends 91264)
    int*   offs    = (int*)(ws + 91264);        // 20001 ints
    int*   cursor  = (int*)(ws + 171280);       // 20000 ints
    float* dinv    = (float*)(ws + 251280);     // 20000
    int*   csr     = (int*)(ws + 331280);       // 320000 ints
    unsigned short* WT   = (unsigned short*)(ws + 1611280);   // 512x256 bf16
    unsigned short* aggX = (unsigned short*)(ws + 1873424);   // 20032x256 bf16
    unsigned short* xb   = (unsigned short*)(ws + 12129808);  // 20000x256 bf16
    float* complete = (float*)(ws + 22369808);  // 1024
    (void)ws_size; (void)in_sizes; (void)n_in; (void)out_size;

    hipMemsetAsync(d_ws, 0, 91264, stream);

    k1_prep<<<6282, 256, 0, stream>>>(edge, x, Wg, cnt, WT, xb);
    k2_scan<<<1, 1024, 0, stream>>>(cnt, offs, cursor, dinv);
    k3_fill<<<1250, 256, 0, stream>>>(edge, cursor, csr);
    k4_agg<<<5008, 256, 0, stream>>>(offs, csr, dinv, xb, aggX);
    k5_gemm<<<dim3(313, 4), 256, 0, stream>>>(aggX, WT, bg, h);
    k_mv<<<dim3(64, 2), 256, 0, stream>>>(h,     nullptr, Wc1, f1raw, 512, 0);
    k_mv<<<dim3(64, 2), 256, 0, stream>>>(f1raw, bc1,     Wc2, f2raw, 512, 1);
    k_mv<<<dim3(64, 2), 256, 0, stream>>>(f2raw, bc2,     Wc3, l3raw, 512, 1);
    k9_mid<<<1, 512, 0, stream>>>(h, c1w, c1b, c2w, c2b, l3raw, bc3, complete);
    k_mv<<<dim3(128, 2), 256, 0, stream>>>(complete, nullptr, Wp1, p1raw, 512, 0);
    k_mv<<<dim3(64, 1), 256, 0, stream>>>(p1raw, bp1, Wp2, p2raw, 256, 1);
    k12_final<<<1, 256, 0, stream>>>(p2raw, bp2, Wp3, bp3, Wp4, bp4, out);
}